// Round 7
// baseline (486.607 us; speedup 1.0000x reference)
//
#include <hip/hip_runtime.h>
#include <hip/hip_bf16.h>

#define HID   128
#define OUTD  64
#define NPROD 100000
#define NCUST 50000
#define EPP   800000
#define EPC   800000
#define ELB   400000
#define NBK   391      // coarse buckets per graph (pp: K=256 nodes, pc: K=128)
#define EBLK  4096     // edges per bucket3 block
#define RCAP3 512      // slots per (bucket, replica); mean fill ~256
#define BCAP3 2560     // per-bucket LDS capacity in bsort (mean 2046, +11 sigma)
#define CPADN 400      // counter stride (buckets) per replica bank
#define NB3   392      // bucket3 blocks (196 pp + 196 pc)
#define NCAST 6250     // x_prod cast blocks (1.6M int4 / 256)

typedef __bf16 bf16x8 __attribute__((ext_vector_type(8)));
typedef float  f32x4  __attribute__((ext_vector_type(4)));
typedef unsigned short u16;
typedef unsigned int u32;

__device__ __forceinline__ float b2f(u16 u) {
  unsigned int v = ((unsigned int)u) << 16;
  float f; __builtin_memcpy(&f, &v, 4); return f;
}
__device__ __forceinline__ u16 f2b(float f) {
  __hip_bfloat16 h = __float2bfloat16(f);
  u16 u; __builtin_memcpy(&u, &h, 2); return u;
}

union Pack8 { u16 u[8]; int4 v; };

// XOR-swizzled LDS index for 128-col rows (16B chunks, swizzle by row&15).
__device__ __forceinline__ int sidx(int row, int chunk) {
  return row * HID + ((chunk ^ (row & 15)) << 3);
}
// Same for 64-col rows (8 chunks, swizzle by row&7).
__device__ __forceinline__ int sidx64(int row, int chunk) {
  return row * 64 + ((chunk ^ (row & 7)) << 3);
}

// B-fragment directly from global weight matrix W[row][chunk*8..+8).
// Identical bytes to the old sW staging+swizzled read (L2-hot: each W is
// 32 KB read by every block). Removing sW is the R6 occupancy fix:
// k_lay1 LDS 64->32 KB, k_chain2 48->24 KB; dual-output path drops ALL
// inter-phase barriers (reg A-frags + global B = no LDS hazards).
__device__ __forceinline__ bf16x8 wfrag(const u16* __restrict__ W, int row, int chunk) {
  return *(const bf16x8*)(W + (size_t)row * HID + chunk * 8);
}

#define NJOBS 13
struct CastJobs { const float* src[NJOBS]; int n8[NJOBS]; };

// ---------------- merged preprocessing: bucket3 + x_prod cast + weight cast --
__global__ __launch_bounds__(256) void k_prep(const int* __restrict__ ei_pp,
                                              const int* __restrict__ ei_pc,
                                              int* __restrict__ bfill_pp,
                                              int* __restrict__ bfill_pc,
                                              u32* __restrict__ bss_pp,
                                              u32* __restrict__ bss_pc,
                                              const float* __restrict__ x_prod,
                                              u16* __restrict__ XPB,
                                              CastJobs jobs,
                                              u16* __restrict__ wbuf) {
  __shared__ int lcnt[NBK], lstart[NBK], lfill[NBK], gbase[NBK];
  __shared__ u32 spay[EBLK];
  __shared__ u16 sbk[EBLK];
  __shared__ int wtot[4];
  const int t = threadIdx.x;
  int bid = blockIdx.x;

  if (bid >= NB3) {
    bid -= NB3;
    if (bid < NCAST) {                 // fp32 -> bf16 feature cast
      int i = bid * 256 + t;
      float4 a = ((const float4*)x_prod)[2 * i];
      float4 b = ((const float4*)x_prod)[2 * i + 1];
      Pack8 p;
      p.u[0] = f2b(a.x); p.u[1] = f2b(a.y); p.u[2] = f2b(a.z); p.u[3] = f2b(a.w);
      p.u[4] = f2b(b.x); p.u[5] = f2b(b.y); p.u[6] = f2b(b.z); p.u[7] = f2b(b.w);
      ((int4*)XPB)[i] = p.v;
      return;
    }
    bid -= NCAST;                      // weight casts
    int job = bid >> 3;
    int idx = (bid & 7) * 256 + t;
    int off8 = (job < 10) ? job * 2048 : 10 * 2048 + (job - 10) * 1024;
    if (idx >= jobs.n8[job]) return;
    const float* s = jobs.src[job];
    float4 a = ((const float4*)s)[2 * idx];
    float4 b = ((const float4*)s)[2 * idx + 1];
    Pack8 p;
    p.u[0] = f2b(a.x); p.u[1] = f2b(a.y); p.u[2] = f2b(a.z); p.u[3] = f2b(a.w);
    p.u[4] = f2b(b.x); p.u[5] = f2b(b.y); p.u[6] = f2b(b.z); p.u[7] = f2b(b.w);
    ((int4*)wbuf)[off8 + idx] = p.v;
    return;
  }

  // ---- CSR pass A: per-block LDS counting sort + batched scatter ----
  const int lane = t & 63, wv = t >> 6;
  int xcc; asm("s_getreg_b32 %0, hwreg(HW_REG_XCC_ID)" : "=s"(xcc));
  const int rep = xcc & 7;
  const int NBLK_PP = (EPP + EBLK - 1) / EBLK;   // 196
  const bool isPP = bid < NBLK_PP;
  const int* ei = isPP ? ei_pp : ei_pc;
  const int E  = isPP ? EPP : EPC;
  const int SH = isPP ? 8 : 7;                   // K = 256 / 128 nodes per bucket
  int* bfill = isPP ? bfill_pp : bfill_pc;
  u32* bss   = isPP ? bss_pp : bss_pc;
  const int base = (isPP ? bid : bid - NBLK_PP) * EBLK;
  const int n = min(EBLK, E - base);

  for (int j = t; j < NBK; j += 256) { lcnt[j] = 0; lfill[j] = 0; }
  __syncthreads();

  // vectorized edge loads: thread t owns 16 CONSECUTIVE edges (4x int4 per
  // stream). Edge->thread order is irrelevant downstream.
  u32 pay[16]; int bk[16];
  const int e0 = t * 16;
  const int* srcp = ei + base;
  const int* dstp = ei + E + base;
  #pragma unroll
  for (int i = 0; i < 16; ++i) bk[i] = -1;
  if (e0 < n) {
    #pragma unroll
    for (int i = 0; i < 4; ++i) {
      int4 s4 = *(const int4*)(srcp + e0 + i * 4);
      int4 d4 = *(const int4*)(dstp + e0 + i * 4);
      int ss[4] = {s4.x, s4.y, s4.z, s4.w};
      int dd[4] = {d4.x, d4.y, d4.z, d4.w};
      #pragma unroll
      for (int j = 0; j < 4; ++j) {
        int b = dd[j] >> SH;
        bk[i * 4 + j] = b;
        pay[i * 4 + j] = ((u32)ss[j] << SH) | (u32)(dd[j] & ((1 << SH) - 1));
        atomicAdd(&lcnt[b], 1);
      }
    }
  }
  __syncthreads();
  // parallel exclusive scan of lcnt (2 entries/thread, shfl wave scan)
  {
    int a0 = (2 * t < NBK) ? lcnt[2 * t] : 0;
    int a1 = (2 * t + 1 < NBK) ? lcnt[2 * t + 1] : 0;
    int s = a0 + a1;
    #pragma unroll
    for (int d = 1; d < 64; d <<= 1) {
      int u = __shfl_up(s, d, 64);
      if (lane >= d) s += u;
    }
    if (lane == 63) wtot[wv] = s;
    __syncthreads();
    int wpre = 0;
    for (int w = 0; w < wv; ++w) wpre += wtot[w];
    int excl = s + wpre - (a0 + a1);
    if (2 * t < NBK) lstart[2 * t] = excl;
    if (2 * t + 1 < NBK) lstart[2 * t + 1] = excl + a0;
  }
  __syncthreads();
  // one global atomic per nonempty bucket reserves the run
  for (int b = t; b < NBK; b += 256) {
    int c = lcnt[b];
    gbase[b] = c ? atomicAdd(&bfill[(rep * CPADN + b) << 4], c) : 0;
  }
  // LDS scatter sorted by bucket
  #pragma unroll
  for (int i = 0; i < 16; ++i) {
    if (bk[i] >= 0) {
      int pos = lstart[bk[i]] + atomicAdd(&lfill[bk[i]], 1);
      spay[pos] = pay[i];
      sbk[pos] = (u16)bk[i];
    }
  }
  __syncthreads();
  // coalesced run writeout
  for (int i = t; i < n; i += 256) {
    int b = sbk[i];
    int slot = gbase[b] + (i - lstart[b]);
    if (slot < RCAP3)
      bss[(b * 8 + rep) * RCAP3 + slot] = spay[i];
  }
}

// ---------------- CSR pass B: merged pp+pc fine counting sort ---------------
__global__ __launch_bounds__(256) void k_bsort2(const u32* __restrict__ bss_pp,
                                                const int* __restrict__ bfill_pp,
                                                const u32* __restrict__ bss_pc,
                                                const int* __restrict__ bfill_pc,
                                                int* __restrict__ gctr,
                                                int* __restrict__ esrc_pp,
                                                int* __restrict__ start_pp,
                                                int* __restrict__ cnt_pp,
                                                int* __restrict__ esrc_pc,
                                                int* __restrict__ start_pc,
                                                int* __restrict__ cnt_pc) {
  __shared__ u32 pairs[BCAP3];
  __shared__ int outsrc[BCAP3];
  __shared__ int lcnt[256], lstart[256], lfill[256];
  __shared__ int sh_n, sh_base, rn[8], roff[8], wtot[4];
  const int tid = threadIdx.x;
  const int lane = tid & 63, wv = tid >> 6;
  const bool isPP = (int)blockIdx.x < NBK;
  const int b = isPP ? (int)blockIdx.x : (int)blockIdx.x - NBK;
  const int K   = isPP ? 256 : 128;
  const int SHL = isPP ? 8 : 7;
  const u32* bss   = isPP ? bss_pp : bss_pc;
  const int* bfill = isPP ? bfill_pp : bfill_pc;
  int* gc    = isPP ? gctr : gctr + 1;
  int* esrc  = isPP ? esrc_pp : esrc_pc;
  int* start = isPP ? start_pp : start_pc;
  int* cnt   = isPP ? cnt_pp : cnt_pc;
  const int n_nodes = isPP ? NPROD : NCUST;

  if (tid < 8) rn[tid] = min(bfill[(tid * CPADN + b) << 4], RCAP3);
  for (int j = tid; j < K; j += 256) { lcnt[j] = 0; lfill[j] = 0; }
  __syncthreads();
  if (tid == 0) {
    int run = 0;
    for (int r = 0; r < 8; ++r) {
      roff[r] = run;
      int m = min(rn[r], BCAP3 - run);
      rn[r] = m;
      run += m;
    }
    sh_n = run;
    sh_base = atomicAdd(gc, run);
  }
  __syncthreads();
  const int n = sh_n, base = sh_base;
  const int Km1 = K - 1;
  #pragma unroll
  for (int r = 0; r < 8; ++r) {
    int m = rn[r], o = roff[r];
    for (int i = tid; i < m; i += 256) {
      u32 p = bss[(b * 8 + r) * RCAP3 + i];
      pairs[o + i] = p;
      atomicAdd(&lcnt[p & Km1], 1);
    }
  }
  __syncthreads();
  // parallel exclusive scan of lcnt[0..K)
  {
    int a0 = (2 * tid < K) ? lcnt[2 * tid] : 0;
    int a1 = (2 * tid + 1 < K) ? lcnt[2 * tid + 1] : 0;
    int s = a0 + a1;
    #pragma unroll
    for (int d = 1; d < 64; d <<= 1) {
      int u = __shfl_up(s, d, 64);
      if (lane >= d) s += u;
    }
    if (lane == 63) wtot[wv] = s;
    __syncthreads();
    int wpre = 0;
    for (int w = 0; w < wv; ++w) wpre += wtot[w];
    int excl = s + wpre - (a0 + a1);
    if (2 * tid < K) lstart[2 * tid] = excl;
    if (2 * tid + 1 < K) lstart[2 * tid + 1] = excl + a0;
  }
  __syncthreads();
  for (int i = tid; i < n; i += 256) {
    u32 p = pairs[i];
    int ln = p & Km1;
    int pos = lstart[ln] + atomicAdd(&lfill[ln], 1);
    outsrc[pos] = (int)(p >> SHL);
  }
  __syncthreads();
  for (int i = tid; i < n; i += 256) esrc[base + i] = outsrc[i];
  const int nb0 = b * K;
  for (int j = tid; j < K; j += 256) {
    int g = nb0 + j;
    if (g < n_nodes) { start[g] = base + lstart[j]; cnt[g] = lcnt[j]; }
  }
}

// ---------------- combined mean aggregation (quarter-wave per node, x4 MLP) ----
// NOTE (R1 post-mortem): column-slicing this gather (32 B pieces) over-fetched
// 128 B sectors -> 705 MB vs 258 MB and 2.6x slower. Full-row 256 B gathers at
// ~3.65 TB/s are within ~1.45x of the per-XCD-perfect-caching fabric bound;
// keep this kernel as-is. (R5 split diag cost ~8 us; recombined in R6.)
__global__ __launch_bounds__(256) void k_agg2(const int* __restrict__ es_a,
                                              const int* __restrict__ st_a,
                                              const int* __restrict__ cn_a,
                                              const u16* __restrict__ xa,
                                              u16* __restrict__ oa, int na,
                                              const int* __restrict__ es_b,
                                              const int* __restrict__ st_b,
                                              const int* __restrict__ cn_b,
                                              const u16* __restrict__ xb,
                                              u16* __restrict__ ob, int nb, int blkA) {
  const int t = threadIdx.x;
  const bool A = (int)blockIdx.x < blkA;
  const int node = (A ? (int)blockIdx.x : (int)blockIdx.x - blkA) * 16 + (t >> 4);
  const int l16 = t & 15;
  const int q4  = t & 48;
  if (node >= (A ? na : nb)) return;
  const int* esrc  = A ? es_a : es_b;
  const u16* x     = A ? xa : xb;
  u16* outm        = A ? oa : ob;
  int s0 = (A ? st_a : st_b)[node];
  int c  = (A ? cn_a : cn_b)[node];
  float acc[8] = {0.f, 0.f, 0.f, 0.f, 0.f, 0.f, 0.f, 0.f};
  for (int j0 = 0; j0 < c; j0 += 16) {
    int nch = min(16, c - j0);
    int eid = (l16 < nch) ? esrc[s0 + j0 + l16] : 0;
    int k = 0;
    for (; k + 4 <= nch; k += 4) {   // 4 independent loads in flight
      int s0i = __shfl(eid, q4 + k, 64);
      int s1i = __shfl(eid, q4 + k + 1, 64);
      int s2i = __shfl(eid, q4 + k + 2, 64);
      int s3i = __shfl(eid, q4 + k + 3, 64);
      Pack8 p0, p1, p2, p3;
      p0.v = *(const int4*)(x + (size_t)s0i * HID + l16 * 8);
      p1.v = *(const int4*)(x + (size_t)s1i * HID + l16 * 8);
      p2.v = *(const int4*)(x + (size_t)s2i * HID + l16 * 8);
      p3.v = *(const int4*)(x + (size_t)s3i * HID + l16 * 8);
      #pragma unroll
      for (int u = 0; u < 8; ++u)
        acc[u] += (b2f(p0.u[u]) + b2f(p1.u[u])) + (b2f(p2.u[u]) + b2f(p3.u[u]));
    }
    for (; k < nch; ++k) {
      int s = __shfl(eid, q4 + k, 64);
      Pack8 p;
      p.v = *(const int4*)(x + (size_t)s * HID + l16 * 8);
      #pragma unroll
      for (int u = 0; u < 8; ++u) acc[u] += b2f(p.u[u]);
    }
  }
  float inv = 1.0f / (float)max(c, 1);
  Pack8 o;
  #pragma unroll
  for (int u = 0; u < 8; ++u) o.u[u] = f2b(acc[u] * inv);
  *(int4*)(outm + (size_t)node * HID + l16 * 8) = o.v;
}

// ---------------- merged layer-1 GEMMs: cx (dual-K) + p1/px (dual-output) ----
// R6: weights read as B-fragments DIRECT FROM GLOBAL (L2-hot, bit-identical)
// -> no sW, LDS 64->32 KB, dual-output path has a single barrier total.
__global__ __launch_bounds__(256) void k_lay1(
    const u16* __restrict__ cxA1, const u16* __restrict__ cxW1,
    const float* __restrict__ cxA2f, const u16* __restrict__ cxW2,
    const float* __restrict__ cxBias, u16* __restrict__ cxOut, int Mcx,
    const u16* __restrict__ A1, const u16* __restrict__ A2,
    const u16* __restrict__ Wa, const u16* __restrict__ Wb,
    const u16* __restrict__ Wc, const u16* __restrict__ Wd,
    const float* __restrict__ bias1, const float* __restrict__ bias2,
    u16* __restrict__ out1, u16* __restrict__ out2, int M2o,
    int blkCx) {
  __shared__ __align__(16) u16 sA1[64 * HID];
  __shared__ __align__(16) u16 sA2[64 * HID];
  const int tid  = threadIdx.x;
  const int lane = tid & 63;
  const int wave = tid >> 6;
  const int q    = lane >> 4;
  const int r16  = lane & 15;
  const bool isCx = (int)blockIdx.x < blkCx;

  if (isCx) {
    // ---- dual-K GEMM (cx) ----
    const int m0 = blockIdx.x * 64;
    f32x4 acc[4][2];
    #pragma unroll
    for (int i = 0; i < 4; ++i)
      #pragma unroll
      for (int j = 0; j < 2; ++j) {
        acc[i][j][0] = 0.f; acc[i][j][1] = 0.f; acc[i][j][2] = 0.f; acc[i][j][3] = 0.f;
      }
    #pragma unroll
    for (int phase = 0; phase < 2; ++phase) {
      const u16* W = phase ? cxW2 : cxW1;
      if (phase) __syncthreads();
      #pragma unroll
      for (int i = 0; i < 4; ++i) {
        int idx = i * 256 + tid;
        int rr = idx >> 4, c8 = idx & 15;
        int gr = m0 + rr;
        Pack8 p; p.v = make_int4(0, 0, 0, 0);
        if (gr < Mcx) {
          if (phase == 0) {
            p.v = *(const int4*)(cxA1 + (size_t)gr * HID + c8 * 8);
          } else {
            const float* s = cxA2f + (size_t)gr * HID + c8 * 8;
            float4 f0 = ((const float4*)s)[0], f1 = ((const float4*)s)[1];
            p.u[0] = f2b(f0.x); p.u[1] = f2b(f0.y); p.u[2] = f2b(f0.z); p.u[3] = f2b(f0.w);
            p.u[4] = f2b(f1.x); p.u[5] = f2b(f1.y); p.u[6] = f2b(f1.z); p.u[7] = f2b(f1.w);
          }
        }
        *(int4*)(sA1 + sidx(rr, c8)) = p.v;
      }
      __syncthreads();
      #pragma unroll
      for (int ks = 0; ks < 4; ++ks) {
        int chunk = ks * 4 + q;
        bf16x8 a[4], b[2];
        #pragma unroll
        for (int mi = 0; mi < 4; ++mi)
          a[mi] = *(const bf16x8*)(sA1 + sidx(mi * 16 + r16, chunk));
        #pragma unroll
        for (int ni = 0; ni < 2; ++ni)
          b[ni] = wfrag(W, wave * 32 + ni * 16 + r16, chunk);
        #pragma unroll
        for (int mi = 0; mi < 4; ++mi)
          #pragma unroll
          for (int ni = 0; ni < 2; ++ni)
            acc[mi][ni] = __builtin_amdgcn_mfma_f32_16x16x32_bf16(a[mi], b[ni], acc[mi][ni], 0, 0, 0);
      }
    }
    #pragma unroll
    for (int ni = 0; ni < 2; ++ni) {
      int col = wave * 32 + ni * 16 + r16;
      float bv = cxBias[col];
      #pragma unroll
      for (int mi = 0; mi < 4; ++mi)
        #pragma unroll
        for (int r = 0; r < 4; ++r) {
          int gr = m0 + mi * 16 + q * 4 + r;
          if (gr < Mcx)
            cxOut[(size_t)gr * HID + col] = f2b(fmaxf(acc[mi][ni][r] + bv, 0.f));
        }
    }
    return;
  }

  // ---- dual-output GEMM (p1/px): ONE barrier, zero LDS traffic after ----
  const int m0 = ((int)blockIdx.x - blkCx) * 64;
  f32x4 acc1[4][2], acc2[4][2];
  #pragma unroll
  for (int i = 0; i < 4; ++i)
    #pragma unroll
    for (int j = 0; j < 2; ++j) {
      acc1[i][j][0] = 0.f; acc1[i][j][1] = 0.f; acc1[i][j][2] = 0.f; acc1[i][j][3] = 0.f;
      acc2[i][j][0] = 0.f; acc2[i][j][1] = 0.f; acc2[i][j][2] = 0.f; acc2[i][j][3] = 0.f;
    }

  // stage both A tiles once
  #pragma unroll
  for (int i = 0; i < 4; ++i) {
    int idx = i * 256 + tid;
    int rr = idx >> 4, c8 = idx & 15;
    int gr = m0 + rr;
    Pack8 p1, p2;
    p1.v = make_int4(0, 0, 0, 0);
    p2.v = make_int4(0, 0, 0, 0);
    if (gr < M2o) {
      p1.v = *(const int4*)(A1 + (size_t)gr * HID + c8 * 8);
      p2.v = *(const int4*)(A2 + (size_t)gr * HID + c8 * 8);
    }
    *(int4*)(sA1 + sidx(rr, c8)) = p1.v;
    *(int4*)(sA2 + sidx(rr, c8)) = p2.v;
  }
  __syncthreads();

  bf16x8 af[4][4];   // [ks][mi] register-cached A fragments

  auto loadA = [&](const u16* sA) {
    #pragma unroll
    for (int ks = 0; ks < 4; ++ks)
      #pragma unroll
      for (int mi = 0; mi < 4; ++mi)
        af[ks][mi] = *(const bf16x8*)(sA + sidx(mi * 16 + r16, ks * 4 + q));
  };
  auto mfW = [&](f32x4 (&acc)[4][2], const u16* W) {
    #pragma unroll
    for (int ks = 0; ks < 4; ++ks) {
      int chunk = ks * 4 + q;
      bf16x8 b[2];
      #pragma unroll
      for (int ni = 0; ni < 2; ++ni)
        b[ni] = wfrag(W, wave * 32 + ni * 16 + r16, chunk);
      #pragma unroll
      for (int mi = 0; mi < 4; ++mi)
        #pragma unroll
        for (int ni = 0; ni < 2; ++ni)
          acc[mi][ni] = __builtin_amdgcn_mfma_f32_16x16x32_bf16(af[ks][mi], b[ni], acc[mi][ni], 0, 0, 0);
    }
  };

  loadA(sA1);           // A1 feeds acc1 (Wa) then acc2 (Wc)
  mfW(acc1, Wa);
  mfW(acc2, Wc);
  loadA(sA2);           // A2 feeds acc1 (Wb) then acc2 (Wd)
  mfW(acc1, Wb);
  mfW(acc2, Wd);

  #pragma unroll
  for (int ni = 0; ni < 2; ++ni) {
    int col = wave * 32 + ni * 16 + r16;
    float bv1 = bias1[col];
    float bv2 = bias2[col];
    #pragma unroll
    for (int mi = 0; mi < 4; ++mi)
      #pragma unroll
      for (int r = 0; r < 4; ++r) {
        int gr = m0 + mi * 16 + q * 4 + r;
        if (gr < M2o) {
          out1[(size_t)gr * HID + col] = f2b(fmaxf(acc1[mi][ni][r] + bv1, 0.f));
          out2[(size_t)gr * HID + col] = f2b(fmaxf(acc2[mi][ni][r] + bv2, 0.f));
        }
      }
  }
}

// ---------------- merged dual chain GEMM: us-chain + it-chain, one launch ----
// R6: all weights (W1/W2/Wlin/dW1) as direct-global B-fragments; LDS is sA
// (A tile, then T) + sZ (Z tile) = 24 KB (was 48).
__global__ __launch_bounds__(256) void k_chain2(
    const u16* __restrict__ A1a, const u16* __restrict__ W1a,
    const u16* __restrict__ A2a, const u16* __restrict__ W2a,
    const float* __restrict__ biasa, u16* __restrict__ outa, int Ma,
    const u16* __restrict__ Wlina, const float* __restrict__ blina,
    const u16* __restrict__ dW1a, const float* __restrict__ db1a,
    const u16* __restrict__ A1b, const u16* __restrict__ W1b,
    const u16* __restrict__ A2b, const u16* __restrict__ W2b,
    const float* __restrict__ biasb, u16* __restrict__ outb, int Mb,
    const u16* __restrict__ Wlinb, const float* __restrict__ blinb,
    const u16* __restrict__ dW1b, const float* __restrict__ db1b,
    int blkA) {
  __shared__ __align__(16) u16 sA[64 * HID];
  __shared__ __align__(16) u16 sZ[64 * 64];
  const bool isA = (int)blockIdx.x < blkA;
  const u16* A1 = isA ? A1a : A1b;
  const u16* W1 = isA ? W1a : W1b;
  const u16* A2 = isA ? A2a : A2b;
  const u16* W2 = isA ? W2a : W2b;
  const float* bias = isA ? biasa : biasb;
  u16* out = isA ? outa : outb;
  const int M = isA ? Ma : Mb;
  const u16* Wlin = isA ? Wlina : Wlinb;
  const float* blin = isA ? blina : blinb;
  const u16* dW1 = isA ? dW1a : dW1b;
  const float* db1 = isA ? db1a : db1b;

  const int tid  = threadIdx.x;
  const int lane = tid & 63;
  const int wave = tid >> 6;
  const int q    = lane >> 4;
  const int r16  = lane & 15;
  const int m0   = (isA ? (int)blockIdx.x : (int)blockIdx.x - blkA) * 64;

  f32x4 acc[4][2];
  #pragma unroll
  for (int i = 0; i < 4; ++i)
    #pragma unroll
    for (int j = 0; j < 2; ++j) {
      acc[i][j][0] = 0.f; acc[i][j][1] = 0.f; acc[i][j][2] = 0.f; acc[i][j][3] = 0.f;
    }

  #pragma unroll
  for (int phase = 0; phase < 2; ++phase) {
    const u16* W = phase ? W2 : W1;
    const u16* A = phase ? A2 : A1;
    if (phase) __syncthreads();
    #pragma unroll
    for (int i = 0; i < 4; ++i) {
      int idx = i * 256 + tid;
      int rr = idx >> 4, c8 = idx & 15;
      int gr = m0 + rr;
      Pack8 p; p.v = make_int4(0, 0, 0, 0);
      if (gr < M) p.v = *(const int4*)(A + (size_t)gr * HID + c8 * 8);
      *(int4*)(sA + sidx(rr, c8)) = p.v;
    }
    __syncthreads();
    #pragma unroll
    for (int ks = 0; ks < 4; ++ks) {
      int chunk = ks * 4 + q;
      bf16x8 a[4], b[2];
      #pragma unroll
      for (int mi = 0; mi < 4; ++mi)
        a[mi] = *(const bf16x8*)(sA + sidx(mi * 16 + r16, chunk));
      #pragma unroll
      for (int ni = 0; ni < 2; ++ni)
        b[ni] = wfrag(W, wave * 32 + ni * 16 + r16, chunk);
      #pragma unroll
      for (int mi = 0; mi < 4; ++mi)
        #pragma unroll
        for (int ni = 0; ni < 2; ++ni)
          acc[mi][ni] = __builtin_amdgcn_mfma_f32_16x16x32_bf16(a[mi], b[ni], acc[mi][ni], 0, 0, 0);
    }
  }

  // chain epilogue: T(relu) -> Z -> out
  __syncthreads();
  #pragma unroll
  for (int ni = 0; ni < 2; ++ni) {
    int col = wave * 32 + ni * 16 + r16;
    float bv = bias[col];
    #pragma unroll
    for (int mi = 0; mi < 4; ++mi)
      #pragma unroll
      for (int r = 0; r < 4; ++r) {
        int rl = mi * 16 + q * 4 + r;
        float v = fmaxf(acc[mi][ni][r] + bv, 0.f);
        sA[rl * HID + (((col >> 3) ^ (rl & 15)) << 3) + (col & 7)] = f2b(v);
      }
  }
  __syncthreads();
  f32x4 az[4];
  #pragma unroll
  for (int i = 0; i < 4; ++i) { az[i][0]=0.f; az[i][1]=0.f; az[i][2]=0.f; az[i][3]=0.f; }
  #pragma unroll
  for (int ks = 0; ks < 4; ++ks) {
    int chunk = ks * 4 + q;
    bf16x8 b = wfrag(Wlin, wave * 16 + r16, chunk);
    #pragma unroll
    for (int mi = 0; mi < 4; ++mi) {
      bf16x8 a = *(const bf16x8*)(sA + sidx(mi * 16 + r16, chunk));
      az[mi] = __builtin_amdgcn_mfma_f32_16x16x32_bf16(a, b, az[mi], 0, 0, 0);
    }
  }
  {
    int col = wave * 16 + r16;
    float bl = blin[col];
    #pragma unroll
    for (int mi = 0; mi < 4; ++mi)
      #pragma unroll
      for (int r = 0; r < 4; ++r) {
        int rl = mi * 16 + q * 4 + r;
        sZ[rl * 64 + (((col >> 3) ^ (rl & 7)) << 3) + (col & 7)] = f2b(az[mi][r] + bl);
      }
  }
  __syncthreads();
  f32x4 au[4];
  #pragma unroll
  for (int i = 0; i < 4; ++i) { au[i][0]=0.f; au[i][1]=0.f; au[i][2]=0.f; au[i][3]=0.f; }
  #pragma unroll
  for (int ks = 0; ks < 2; ++ks) {
    int chunk = ks * 4 + q;
    bf16x8 b = wfrag(dW1, wave * 16 + r16, chunk);
    #pragma unroll
    for (int mi = 0; mi < 4; ++mi) {
      bf16x8 a = *(const bf16x8*)(sZ + sidx64(mi * 16 + r16, chunk));
      au[mi] = __builtin_amdgcn_mfma_f32_16x16x32_bf16(a, b, au[mi], 0, 0, 0);
    }
  }
  {
    int col = wave * 16 + r16;
    float db = db1 ? db1[col] : 0.f;
    #pragma unroll
    for (int mi = 0; mi < 4; ++mi)
      #pragma unroll
      for (int r = 0; r < 4; ++r) {
        int gr = m0 + mi * 16 + q * 4 + r;
        if (gr < M) out[(size_t)gr * 64 + col] = f2b(au[mi][r] + db);
      }
  }
}

// ---------------- edge scorer: out[e] = w2 . relu(U[row]+V[col]) + b2 ---------
__global__ __launch_bounds__(256) void k_edge(const u16* __restrict__ U,
                                              const u16* __restrict__ V,
                                              const int* __restrict__ eli,
                                              const float* __restrict__ w2,
                                              const float* __restrict__ b2,
                                              float* __restrict__ out) {
  const int lane = threadIdx.x & 63;
  const int wave = threadIdx.x >> 6;
  const int se   = (lane >> 3);
  const int ch   = lane & 7;
  float w2c[8];
  #pragma unroll
  for (int j = 0; j < 8; ++j) w2c[j] = w2[ch * 8 + j];
  const float b2v = b2[0];
  const int e0 = blockIdx.x * 256;
  #pragma unroll
  for (int p = 0; p < 8; ++p) {
    int e = e0 + p * 32 + wave * 8 + se;
    if (e < ELB) {
      int r = eli[e];
      int c = eli[ELB + e];
      Pack8 pu, pv;
      pu.v = *(const int4*)(U + (size_t)r * 64 + ch * 8);
      pv.v = *(const int4*)(V + (size_t)c * 64 + ch * 8);
      float s = 0.f;
      #pragma unroll
      for (int j = 0; j < 8; ++j)
        s += fmaxf(b2f(pu.u[j]) + b2f(pv.u[j]), 0.f) * w2c[j];
      s += __shfl_xor(s, 1, 64);
      s += __shfl_xor(s, 2, 64);
      s += __shfl_xor(s, 4, 64);
      if (ch == 0) out[e] = s + b2v;
    }
  }
}

extern "C" void kernel_launch(void* const* d_in, const int* in_sizes, int n_in,
                              void* d_out, int out_size, void* d_ws, size_t ws_size,
                              hipStream_t stream) {
  const float* x_prod = (const float*)d_in[0];
  const float* x_cust = (const float*)d_in[1];
  const int* ei_pp    = (const int*)d_in[2];
  const int* ei_pc    = (const int*)d_in[3];
  const int* eli      = (const int*)d_in[4];

  const float *it_W1l, *it_W1r, *it_b1, *it_W2l, *it_W2r, *it_b2, *it_Wlin, *it_blin;
  const float *us_W1l, *us_W1r, *us_b1, *us_W2l, *us_W2r, *us_b2;
  const float *us_W3l, *us_W3r, *us_b3, *us_Wlin, *us_blin;
  if (in_sizes[6] == 128) {   // signature order (Wl, b, Wr)
    it_W1l  = (const float*)d_in[5];  it_b1   = (const float*)d_in[6];  it_W1r  = (const float*)d_in[7];
    it_W2l  = (const float*)d_in[8];  it_b2   = (const float*)d_in[9];  it_W2r  = (const float*)d_in[10];
    it_Wlin = (const float*)d_in[11]; it_blin = (const float*)d_in[12];
    us_W1l  = (const float*)d_in[13]; us_b1   = (const float*)d_in[14]; us_W1r  = (const float*)d_in[15];
    us_W2l  = (const float*)d_in[16]; us_b2   = (const float*)d_in[17]; us_W2r  = (const float*)d_in[18];
    us_W3l  = (const float*)d_in[19]; us_b3   = (const float*)d_in[20]; us_W3r  = (const float*)d_in[21];
    us_Wlin = (const float*)d_in[22]; us_blin = (const float*)d_in[23];
  } else {                    // setup_inputs dict order (Wl, Wr, b)
    it_W1l  = (const float*)d_in[5];  it_W1r  = (const float*)d_in[6];  it_b1   = (const float*)d_in[7];
    it_W2l  = (const float*)d_in[8];  it_W2r  = (const float*)d_in[9];  it_b2   = (const float*)d_in[10];
    it_Wlin = (const float*)d_in[11]; it_blin = (const float*)d_in[12];
    us_W1l  = (const float*)d_in[13]; us_W1r  = (const float*)d_in[14]; us_b1   = (const float*)d_in[15];
    us_W2l  = (const float*)d_in[16]; us_W2r  = (const float*)d_in[17]; us_b2   = (const float*)d_in[18];
    us_W3l  = (const float*)d_in[19]; us_W3r  = (const float*)d_in[20]; us_b3   = (const float*)d_in[21];
    us_Wlin = (const float*)d_in[22]; us_blin = (const float*)d_in[23];
  }
  const float* de_W1 = (const float*)d_in[24];
  const float* de_b1 = (const float*)d_in[25];
  const float* de_W2 = (const float*)d_in[26];
  const float* de_b2 = (const float*)d_in[27];

  char* ws = (char*)d_ws;
  int* bfill_pp = (int*)(ws + 0);              // 8*400*16*4 = 204800 B used (line-padded)
  int* bfill_pc = (int*)(ws + 409600);
  int* gctr     = (int*)(ws + 819200);         // 8 B (memset 0..819208)
  int* start_pp = (int*)(ws + 819264);
  int* cnt_pp   = (int*)(ws + 1219264);
  int* start_pc = (int*)(ws + 1619264);
  int* cnt_pc   = (int*)(ws + 1819264);
  int* esrc_pp  = (int*)(ws + 2019264);        // 3.2 MB \ U overlays after layer-2 aggs
  int* esrc_pc  = (int*)(ws + 5219264);        // 3.2 MB /
  u16* wbuf  = (u16*)(ws + 8419264);           // 376832 B
  u16* XPB   = (u16*)(ws + 8796096);           // 25.6 MB: bf16 x_prod -> PX (in place)
  u16* meanb = (u16*)(ws + 34396096);          // 25.6 MB: mean_pp1 -> mean_pp2
  u16* P1    = (u16*)(ws + 59996096);          // 25.6 MB: bss -> p1
  u16* meanc = (u16*)(ws + 85596096);          // 12.8 MB: mean_pc1 -> mean_pc2
  u16* CX    = (u16*)(ws + 98396096);          // 12.8 MB: cx -> V (peak ~111.2 MB)
  u32* bss_pp = (u32*)P1;                      // 391*8*512*4 = 6.1 MB
  u32* bss_pc = (u32*)(ws + 59996096 + 6553600);
  u16* PX = XPB;
  u16* U  = (u16*)esrc_pp;                     // 50000*64*2 = 6.4 MB exact
  u16* V  = CX;                                // 100000*64*2 = 12.8 MB exact

  u16* w_it1l = wbuf + 0 * 16384;  u16* w_it1r = wbuf + 1 * 16384;
  u16* w_it2l = wbuf + 2 * 16384;  u16* w_it2r = wbuf + 3 * 16384;
  u16* w_us1l = wbuf + 4 * 16384;  u16* w_us1r = wbuf + 5 * 16384;
  u16* w_us2l = wbuf + 6 * 16384;  u16* w_us2r = wbuf + 7 * 16384;
  u16* w_us3l = wbuf + 8 * 16384;  u16* w_us3r = wbuf + 9 * 16384;
  u16* w_itlin = wbuf + 10 * 16384;
  u16* w_uslin = wbuf + 10 * 16384 + 8192;
  u16* w_deW1  = wbuf + 10 * 16384 + 2 * 8192;

  (void)n_in; (void)out_size; (void)ws_size;

  hipMemsetAsync(d_ws, 0, 819208, stream);

  dim3 B(256);
  CastJobs jobs;
  jobs.src[0] = it_W1l;  jobs.src[1] = it_W1r;  jobs.src[2] = it_W2l;  jobs.src[3] = it_W2r;
  jobs.src[4] = us_W1l;  jobs.src[5] = us_W1r;  jobs.src[6] = us_W2l;  jobs.src[7] = us_W2r;
  jobs.src[8] = us_W3l;  jobs.src[9] = us_W3r;
  jobs.src[10] = it_Wlin; jobs.src[11] = us_Wlin; jobs.src[12] = de_W1;
  for (int i = 0; i < 10; ++i) jobs.n8[i] = 2048;
  for (int i = 10; i < 13; ++i) jobs.n8[i] = 1024;

  // merged preprocessing: bucket3 (392) + x_prod cast (6250) + weight cast (104)
  k_prep<<<dim3(NB3 + NCAST + NJOBS * 8), B, 0, stream>>>(
      ei_pp, ei_pc, bfill_pp, bfill_pc, bss_pp, bss_pc, x_prod, XPB, jobs, wbuf);
  // merged fine sort: pp (391) + pc (391)
  k_bsort2<<<dim3(2 * NBK), B, 0, stream>>>(bss_pp, bfill_pp, bss_pc, bfill_pc, gctr,
                                            esrc_pp, start_pp, cnt_pp,
                                            esrc_pc, start_pc, cnt_pc);

  dim3 Gp((NPROD + 63) / 64), Gc((NCUST + 63) / 64);
  const int App = (NPROD + 15) / 16, Apc = (NCUST + 15) / 16;

  // layer-1 means (pp + pc in one launch)
  k_agg2<<<dim3(App + Apc), B, 0, stream>>>(esrc_pp, start_pp, cnt_pp, XPB, meanb, NPROD,
                                            esrc_pc, start_pc, cnt_pc, XPB, meanc, NCUST, App);
  // merged layer-1 GEMMs: cx (782 blocks) + p1/px dual-output (1563 blocks)
  k_lay1<<<dim3(782 + 1563), B, 0, stream>>>(
      meanc, w_us2l, x_cust, w_us2r, us_b2, CX, NCUST,
      meanb, XPB, w_it1l, w_it1r, w_us1l, w_us1r,
      it_b1, us_b1, P1, PX, NPROD, 782);
  // layer-2 means (pp from P1, pc from PX, one launch)
  k_agg2<<<dim3(App + Apc), B, 0, stream>>>(esrc_pp, start_pp, cnt_pp, P1, meanb, NPROD,
                                            esrc_pc, start_pc, cnt_pc, PX, meanc, NCUST, App);
  // merged chains: us (cx2 -> z_cust -> U) + it (p2 -> z_prod -> V)
  k_chain2<<<dim3(782 + 1563), B, 0, stream>>>(
      meanc, w_us3l, CX, w_us3r, us_b3, U, NCUST, w_uslin, us_blin, w_deW1, de_b1,
      meanb, w_it2l, P1, w_it2r, it_b2, V, NPROD, w_itlin, it_blin, w_deW1 + 64, nullptr,
      782);
  // edge scoring
  k_edge<<<dim3((ELB + 255) / 256), B, 0, stream>>>(U, V, eli, de_W2, de_b2, (float*)d_out);
}

// Round 8
// 475.845 us; speedup vs baseline: 1.0226x; 1.0226x over previous
//
#include <hip/hip_runtime.h>
#include <hip/hip_bf16.h>

#define HID   128
#define OUTD  64
#define NPROD 100000
#define NCUST 50000
#define EPP   800000
#define EPC   800000
#define ELB   400000
#define NBK   391      // coarse buckets per graph (pp: K=256 nodes, pc: K=128)
#define EBLK  4096     // edges per bucket3 block
#define RCAP3 512      // slots per (bucket, replica); mean fill ~256
#define BCAP3 2560     // per-bucket LDS capacity in bsort (mean 2046, +11 sigma)
#define CPADN 400      // counter stride (buckets) per replica bank
#define NB3   392      // bucket3 blocks (196 pp + 196 pc)
#define NCAST 6250     // x_prod cast blocks (1.6M int4 / 256)

typedef __bf16 bf16x8 __attribute__((ext_vector_type(8)));
typedef float  f32x4  __attribute__((ext_vector_type(4)));
typedef unsigned short u16;
typedef unsigned int u32;

__device__ __forceinline__ float b2f(u16 u) {
  unsigned int v = ((unsigned int)u) << 16;
  float f; __builtin_memcpy(&f, &v, 4); return f;
}
__device__ __forceinline__ u16 f2b(float f) {
  __hip_bfloat16 h = __float2bfloat16(f);
  u16 u; __builtin_memcpy(&u, &h, 2); return u;
}

union Pack8 { u16 u[8]; int4 v; };

// XOR-swizzled LDS index for 128-col rows (16B chunks, swizzle by row&15).
__device__ __forceinline__ int sidx(int row, int chunk) {
  return row * HID + ((chunk ^ (row & 15)) << 3);
}
// Same for 64-col rows (8 chunks, swizzle by row&7).
__device__ __forceinline__ int sidx64(int row, int chunk) {
  return row * 64 + ((chunk ^ (row & 7)) << 3);
}

// NOTE (R6 post-mortem): direct-global W B-fragments (no sW) REGRESSED +8.4us
// end-to-end despite halving LDS -- W has zero intra-block reuse, so sW was
// never about reuse; it converts strided per-lane 16B L2 reads sitting inside
// the dependent MFMA chain into one coalesced burst. Keep sW staging.

#define NJOBS 13
struct CastJobs { const float* src[NJOBS]; int n8[NJOBS]; };

// ---------------- merged preprocessing: bucket3 + x_prod cast + weight cast --
__global__ __launch_bounds__(256) void k_prep(const int* __restrict__ ei_pp,
                                              const int* __restrict__ ei_pc,
                                              int* __restrict__ bfill_pp,
                                              int* __restrict__ bfill_pc,
                                              u32* __restrict__ bss_pp,
                                              u32* __restrict__ bss_pc,
                                              const float* __restrict__ x_prod,
                                              u16* __restrict__ XPB,
                                              CastJobs jobs,
                                              u16* __restrict__ wbuf) {
  __shared__ int lcnt[NBK], lstart[NBK], lfill[NBK], gbase[NBK];
  __shared__ u32 spay[EBLK];
  __shared__ u16 sbk[EBLK];
  __shared__ int wtot[4];
  const int t = threadIdx.x;
  int bid = blockIdx.x;

  if (bid >= NB3) {
    bid -= NB3;
    if (bid < NCAST) {                 // fp32 -> bf16 feature cast
      int i = bid * 256 + t;
      float4 a = ((const float4*)x_prod)[2 * i];
      float4 b = ((const float4*)x_prod)[2 * i + 1];
      Pack8 p;
      p.u[0] = f2b(a.x); p.u[1] = f2b(a.y); p.u[2] = f2b(a.z); p.u[3] = f2b(a.w);
      p.u[4] = f2b(b.x); p.u[5] = f2b(b.y); p.u[6] = f2b(b.z); p.u[7] = f2b(b.w);
      ((int4*)XPB)[i] = p.v;
      return;
    }
    bid -= NCAST;                      // weight casts
    int job = bid >> 3;
    int idx = (bid & 7) * 256 + t;
    int off8 = (job < 10) ? job * 2048 : 10 * 2048 + (job - 10) * 1024;
    if (idx >= jobs.n8[job]) return;
    const float* s = jobs.src[job];
    float4 a = ((const float4*)s)[2 * idx];
    float4 b = ((const float4*)s)[2 * idx + 1];
    Pack8 p;
    p.u[0] = f2b(a.x); p.u[1] = f2b(a.y); p.u[2] = f2b(a.z); p.u[3] = f2b(a.w);
    p.u[4] = f2b(b.x); p.u[5] = f2b(b.y); p.u[6] = f2b(b.z); p.u[7] = f2b(b.w);
    ((int4*)wbuf)[off8 + idx] = p.v;
    return;
  }

  // ---- CSR pass A: per-block LDS counting sort + batched scatter ----
  const int lane = t & 63, wv = t >> 6;
  int xcc; asm("s_getreg_b32 %0, hwreg(HW_REG_XCC_ID)" : "=s"(xcc));
  const int rep = xcc & 7;
  const int NBLK_PP = (EPP + EBLK - 1) / EBLK;   // 196
  const bool isPP = bid < NBLK_PP;
  const int* ei = isPP ? ei_pp : ei_pc;
  const int E  = isPP ? EPP : EPC;
  const int SH = isPP ? 8 : 7;                   // K = 256 / 128 nodes per bucket
  int* bfill = isPP ? bfill_pp : bfill_pc;
  u32* bss   = isPP ? bss_pp : bss_pc;
  const int base = (isPP ? bid : bid - NBLK_PP) * EBLK;
  const int n = min(EBLK, E - base);

  for (int j = t; j < NBK; j += 256) { lcnt[j] = 0; lfill[j] = 0; }
  __syncthreads();

  // vectorized edge loads: thread t owns 16 CONSECUTIVE edges (4x int4 per
  // stream). Edge->thread order is irrelevant downstream.
  u32 pay[16]; int bk[16];
  const int e0 = t * 16;
  const int* srcp = ei + base;
  const int* dstp = ei + E + base;
  #pragma unroll
  for (int i = 0; i < 16; ++i) bk[i] = -1;
  if (e0 < n) {
    #pragma unroll
    for (int i = 0; i < 4; ++i) {
      int4 s4 = *(const int4*)(srcp + e0 + i * 4);
      int4 d4 = *(const int4*)(dstp + e0 + i * 4);
      int ss[4] = {s4.x, s4.y, s4.z, s4.w};
      int dd[4] = {d4.x, d4.y, d4.z, d4.w};
      #pragma unroll
      for (int j = 0; j < 4; ++j) {
        int b = dd[j] >> SH;
        bk[i * 4 + j] = b;
        pay[i * 4 + j] = ((u32)ss[j] << SH) | (u32)(dd[j] & ((1 << SH) - 1));
        atomicAdd(&lcnt[b], 1);
      }
    }
  }
  __syncthreads();
  // parallel exclusive scan of lcnt (2 entries/thread, shfl wave scan)
  {
    int a0 = (2 * t < NBK) ? lcnt[2 * t] : 0;
    int a1 = (2 * t + 1 < NBK) ? lcnt[2 * t + 1] : 0;
    int s = a0 + a1;
    #pragma unroll
    for (int d = 1; d < 64; d <<= 1) {
      int u = __shfl_up(s, d, 64);
      if (lane >= d) s += u;
    }
    if (lane == 63) wtot[wv] = s;
    __syncthreads();
    int wpre = 0;
    for (int w = 0; w < wv; ++w) wpre += wtot[w];
    int excl = s + wpre - (a0 + a1);
    if (2 * t < NBK) lstart[2 * t] = excl;
    if (2 * t + 1 < NBK) lstart[2 * t + 1] = excl + a0;
  }
  __syncthreads();
  // one global atomic per nonempty bucket reserves the run
  for (int b = t; b < NBK; b += 256) {
    int c = lcnt[b];
    gbase[b] = c ? atomicAdd(&bfill[(rep * CPADN + b) << 4], c) : 0;
  }
  // LDS scatter sorted by bucket
  #pragma unroll
  for (int i = 0; i < 16; ++i) {
    if (bk[i] >= 0) {
      int pos = lstart[bk[i]] + atomicAdd(&lfill[bk[i]], 1);
      spay[pos] = pay[i];
      sbk[pos] = (u16)bk[i];
    }
  }
  __syncthreads();
  // coalesced run writeout
  for (int i = t; i < n; i += 256) {
    int b = sbk[i];
    int slot = gbase[b] + (i - lstart[b]);
    if (slot < RCAP3)
      bss[(b * 8 + rep) * RCAP3 + slot] = spay[i];
  }
}

// ---------------- CSR pass B: merged pp+pc fine counting sort ---------------
__global__ __launch_bounds__(256) void k_bsort2(const u32* __restrict__ bss_pp,
                                                const int* __restrict__ bfill_pp,
                                                const u32* __restrict__ bss_pc,
                                                const int* __restrict__ bfill_pc,
                                                int* __restrict__ gctr,
                                                int* __restrict__ esrc_pp,
                                                int* __restrict__ start_pp,
                                                int* __restrict__ cnt_pp,
                                                int* __restrict__ esrc_pc,
                                                int* __restrict__ start_pc,
                                                int* __restrict__ cnt_pc) {
  __shared__ u32 pairs[BCAP3];
  __shared__ int outsrc[BCAP3];
  __shared__ int lcnt[256], lstart[256], lfill[256];
  __shared__ int sh_n, sh_base, rn[8], roff[8], wtot[4];
  const int tid = threadIdx.x;
  const int lane = tid & 63, wv = tid >> 6;
  const bool isPP = (int)blockIdx.x < NBK;
  const int b = isPP ? (int)blockIdx.x : (int)blockIdx.x - NBK;
  const int K   = isPP ? 256 : 128;
  const int SHL = isPP ? 8 : 7;
  const u32* bss   = isPP ? bss_pp : bss_pc;
  const int* bfill = isPP ? bfill_pp : bfill_pc;
  int* gc    = isPP ? gctr : gctr + 1;
  int* esrc  = isPP ? esrc_pp : esrc_pc;
  int* start = isPP ? start_pp : start_pc;
  int* cnt   = isPP ? cnt_pp : cnt_pc;
  const int n_nodes = isPP ? NPROD : NCUST;

  if (tid < 8) rn[tid] = min(bfill[(tid * CPADN + b) << 4], RCAP3);
  for (int j = tid; j < K; j += 256) { lcnt[j] = 0; lfill[j] = 0; }
  __syncthreads();
  if (tid == 0) {
    int run = 0;
    for (int r = 0; r < 8; ++r) {
      roff[r] = run;
      int m = min(rn[r], BCAP3 - run);
      rn[r] = m;
      run += m;
    }
    sh_n = run;
    sh_base = atomicAdd(gc, run);
  }
  __syncthreads();
  const int n = sh_n, base = sh_base;
  const int Km1 = K - 1;
  #pragma unroll
  for (int r = 0; r < 8; ++r) {
    int m = rn[r], o = roff[r];
    for (int i = tid; i < m; i += 256) {
      u32 p = bss[(b * 8 + r) * RCAP3 + i];
      pairs[o + i] = p;
      atomicAdd(&lcnt[p & Km1], 1);
    }
  }
  __syncthreads();
  // parallel exclusive scan of lcnt[0..K)
  {
    int a0 = (2 * tid < K) ? lcnt[2 * tid] : 0;
    int a1 = (2 * tid + 1 < K) ? lcnt[2 * tid + 1] : 0;
    int s = a0 + a1;
    #pragma unroll
    for (int d = 1; d < 64; d <<= 1) {
      int u = __shfl_up(s, d, 64);
      if (lane >= d) s += u;
    }
    if (lane == 63) wtot[wv] = s;
    __syncthreads();
    int wpre = 0;
    for (int w = 0; w < wv; ++w) wpre += wtot[w];
    int excl = s + wpre - (a0 + a1);
    if (2 * tid < K) lstart[2 * tid] = excl;
    if (2 * tid + 1 < K) lstart[2 * tid + 1] = excl + a0;
  }
  __syncthreads();
  for (int i = tid; i < n; i += 256) {
    u32 p = pairs[i];
    int ln = p & Km1;
    int pos = lstart[ln] + atomicAdd(&lfill[ln], 1);
    outsrc[pos] = (int)(p >> SHL);
  }
  __syncthreads();
  for (int i = tid; i < n; i += 256) esrc[base + i] = outsrc[i];
  const int nb0 = b * K;
  for (int j = tid; j < K; j += 256) {
    int g = nb0 + j;
    if (g < n_nodes) { start[g] = base + lstart[j]; cnt[g] = lcnt[j]; }
  }
}

// ---------------- combined mean aggregation (quarter-wave per node, x4 MLP) ----
// NOTE (R1 post-mortem): column-slicing this gather (32 B pieces) over-fetched
// 128 B sectors -> 705 MB vs 258 MB and 2.6x slower. Full-row 256 B gathers at
// ~3.65 TB/s are within ~1.45x of the per-XCD-perfect-caching fabric bound;
// keep this kernel as-is.
__global__ __launch_bounds__(256) void k_agg2(const int* __restrict__ es_a,
                                              const int* __restrict__ st_a,
                                              const int* __restrict__ cn_a,
                                              const u16* __restrict__ xa,
                                              u16* __restrict__ oa, int na,
                                              const int* __restrict__ es_b,
                                              const int* __restrict__ st_b,
                                              const int* __restrict__ cn_b,
                                              const u16* __restrict__ xb,
                                              u16* __restrict__ ob, int nb, int blkA) {
  const int t = threadIdx.x;
  const bool A = (int)blockIdx.x < blkA;
  const int node = (A ? (int)blockIdx.x : (int)blockIdx.x - blkA) * 16 + (t >> 4);
  const int l16 = t & 15;
  const int q4  = t & 48;
  if (node >= (A ? na : nb)) return;
  const int* esrc  = A ? es_a : es_b;
  const u16* x     = A ? xa : xb;
  u16* outm        = A ? oa : ob;
  int s0 = (A ? st_a : st_b)[node];
  int c  = (A ? cn_a : cn_b)[node];
  float acc[8] = {0.f, 0.f, 0.f, 0.f, 0.f, 0.f, 0.f, 0.f};
  for (int j0 = 0; j0 < c; j0 += 16) {
    int nch = min(16, c - j0);
    int eid = (l16 < nch) ? esrc[s0 + j0 + l16] : 0;
    int k = 0;
    for (; k + 4 <= nch; k += 4) {   // 4 independent loads in flight
      int s0i = __shfl(eid, q4 + k, 64);
      int s1i = __shfl(eid, q4 + k + 1, 64);
      int s2i = __shfl(eid, q4 + k + 2, 64);
      int s3i = __shfl(eid, q4 + k + 3, 64);
      Pack8 p0, p1, p2, p3;
      p0.v = *(const int4*)(x + (size_t)s0i * HID + l16 * 8);
      p1.v = *(const int4*)(x + (size_t)s1i * HID + l16 * 8);
      p2.v = *(const int4*)(x + (size_t)s2i * HID + l16 * 8);
      p3.v = *(const int4*)(x + (size_t)s3i * HID + l16 * 8);
      #pragma unroll
      for (int u = 0; u < 8; ++u)
        acc[u] += (b2f(p0.u[u]) + b2f(p1.u[u])) + (b2f(p2.u[u]) + b2f(p3.u[u]));
    }
    for (; k < nch; ++k) {
      int s = __shfl(eid, q4 + k, 64);
      Pack8 p;
      p.v = *(const int4*)(x + (size_t)s * HID + l16 * 8);
      #pragma unroll
      for (int u = 0; u < 8; ++u) acc[u] += b2f(p.u[u]);
    }
  }
  float inv = 1.0f / (float)max(c, 1);
  Pack8 o;
  #pragma unroll
  for (int u = 0; u < 8; ++u) o.u[u] = f2b(acc[u] * inv);
  *(int4*)(outm + (size_t)node * HID + l16 * 8) = o.v;
}

// ---------------- merged layer-1 GEMMs: cx (dual-K) + p1/px (dual-output) ----
// R7: back to LDS-staged W (R6 errata above). Occupancy fix kept via dropping
// sA2 instead: A-fragments are register-hoisted anyway, and the A2 tile loads
// are a one-time bulk load per phase-pair (latency amortized over 128 MFMAs),
// unlike W's in-loop dependent reads. LDS 64 -> 48 KB => 3 blocks/CU.
// A2 re-read 4x across waves = +75 MB L2-hit traffic (~2 us). Bit-identical.
__global__ __launch_bounds__(256) void k_lay1(
    const u16* __restrict__ cxA1, const u16* __restrict__ cxW1,
    const float* __restrict__ cxA2f, const u16* __restrict__ cxW2,
    const float* __restrict__ cxBias, u16* __restrict__ cxOut, int Mcx,
    const u16* __restrict__ A1, const u16* __restrict__ A2,
    const u16* __restrict__ Wa, const u16* __restrict__ Wb,
    const u16* __restrict__ Wc, const u16* __restrict__ Wd,
    const float* __restrict__ bias1, const float* __restrict__ bias2,
    u16* __restrict__ out1, u16* __restrict__ out2, int M2o,
    int blkCx) {
  __shared__ __align__(16) u16 sA1[64 * HID];
  __shared__ __align__(16) u16 sW[128 * HID];
  const int tid  = threadIdx.x;
  const int lane = tid & 63;
  const int wave = tid >> 6;
  const int q    = lane >> 4;
  const int r16  = lane & 15;
  const bool isCx = (int)blockIdx.x < blkCx;

  if (isCx) {
    // ---- dual-K GEMM (cx) ----
    const int m0 = blockIdx.x * 64;
    f32x4 acc[4][2];
    #pragma unroll
    for (int i = 0; i < 4; ++i)
      #pragma unroll
      for (int j = 0; j < 2; ++j) {
        acc[i][j][0] = 0.f; acc[i][j][1] = 0.f; acc[i][j][2] = 0.f; acc[i][j][3] = 0.f;
      }
    #pragma unroll
    for (int phase = 0; phase < 2; ++phase) {
      const u16* W = phase ? cxW2 : cxW1;
      if (phase) __syncthreads();
      #pragma unroll
      for (int i = 0; i < 4; ++i) {
        int idx = i * 256 + tid;
        int rr = idx >> 4, c8 = idx & 15;
        int gr = m0 + rr;
        Pack8 p; p.v = make_int4(0, 0, 0, 0);
        if (gr < Mcx) {
          if (phase == 0) {
            p.v = *(const int4*)(cxA1 + (size_t)gr * HID + c8 * 8);
          } else {
            const float* s = cxA2f + (size_t)gr * HID + c8 * 8;
            float4 f0 = ((const float4*)s)[0], f1 = ((const float4*)s)[1];
            p.u[0] = f2b(f0.x); p.u[1] = f2b(f0.y); p.u[2] = f2b(f0.z); p.u[3] = f2b(f0.w);
            p.u[4] = f2b(f1.x); p.u[5] = f2b(f1.y); p.u[6] = f2b(f1.z); p.u[7] = f2b(f1.w);
          }
        }
        *(int4*)(sA1 + sidx(rr, c8)) = p.v;
      }
      #pragma unroll
      for (int i = 0; i < 8; ++i) {
        int idx = i * 256 + tid;
        int rr = idx >> 4, c8 = idx & 15;
        *(int4*)(sW + sidx(rr, c8)) = *(const int4*)(W + (size_t)rr * HID + c8 * 8);
      }
      __syncthreads();
      #pragma unroll
      for (int ks = 0; ks < 4; ++ks) {
        int chunk = ks * 4 + q;
        bf16x8 a[4], b[2];
        #pragma unroll
        for (int mi = 0; mi < 4; ++mi)
          a[mi] = *(const bf16x8*)(sA1 + sidx(mi * 16 + r16, chunk));
        #pragma unroll
        for (int ni = 0; ni < 2; ++ni)
          b[ni] = *(const bf16x8*)(sW + sidx(wave * 32 + ni * 16 + r16, chunk));
        #pragma unroll
        for (int mi = 0; mi < 4; ++mi)
          #pragma unroll
          for (int ni = 0; ni < 2; ++ni)
            acc[mi][ni] = __builtin_amdgcn_mfma_f32_16x16x32_bf16(a[mi], b[ni], acc[mi][ni], 0, 0, 0);
      }
    }
    #pragma unroll
    for (int ni = 0; ni < 2; ++ni) {
      int col = wave * 32 + ni * 16 + r16;
      float bv = cxBias[col];
      #pragma unroll
      for (int mi = 0; mi < 4; ++mi)
        #pragma unroll
        for (int r = 0; r < 4; ++r) {
          int gr = m0 + mi * 16 + q * 4 + r;
          if (gr < Mcx)
            cxOut[(size_t)gr * HID + col] = f2b(fmaxf(acc[mi][ni][r] + bv, 0.f));
        }
    }
    return;
  }

  // ---- dual-output GEMM (p1/px) ----
  const int m0 = ((int)blockIdx.x - blkCx) * 64;
  f32x4 acc1[4][2], acc2[4][2];
  #pragma unroll
  for (int i = 0; i < 4; ++i)
    #pragma unroll
    for (int j = 0; j < 2; ++j) {
      acc1[i][j][0] = 0.f; acc1[i][j][1] = 0.f; acc1[i][j][2] = 0.f; acc1[i][j][3] = 0.f;
      acc2[i][j][0] = 0.f; acc2[i][j][1] = 0.f; acc2[i][j][2] = 0.f; acc2[i][j][3] = 0.f;
    }

  // stage the A1 tile only (A2 fragments come straight from global)
  #pragma unroll
  for (int i = 0; i < 4; ++i) {
    int idx = i * 256 + tid;
    int rr = idx >> 4, c8 = idx & 15;
    int gr = m0 + rr;
    Pack8 p1; p1.v = make_int4(0, 0, 0, 0);
    if (gr < M2o) p1.v = *(const int4*)(A1 + (size_t)gr * HID + c8 * 8);
    *(int4*)(sA1 + sidx(rr, c8)) = p1.v;
  }

  bf16x8 af[4][4];   // [ks][mi] register-cached A fragments (64 VGPR)

  auto stageW = [&](const u16* W) {
    #pragma unroll
    for (int i = 0; i < 8; ++i) {
      int idx = i * 256 + tid;
      int rr = idx >> 4, c8 = idx & 15;
      *(int4*)(sW + sidx(rr, c8)) = *(const int4*)(W + (size_t)rr * HID + c8 * 8);
    }
  };
  auto loadA1 = [&]() {
    #pragma unroll
    for (int ks = 0; ks < 4; ++ks)
      #pragma unroll
      for (int mi = 0; mi < 4; ++mi)
        af[ks][mi] = *(const bf16x8*)(sA1 + sidx(mi * 16 + r16, ks * 4 + q));
  };
  auto loadA2g = [&]() {
    #pragma unroll
    for (int ks = 0; ks < 4; ++ks)
      #pragma unroll
      for (int mi = 0; mi < 4; ++mi) {
        int gr = m0 + mi * 16 + r16;
        union { int4 v; bf16x8 b; } p;
        p.v = make_int4(0, 0, 0, 0);
        if (gr < M2o) p.v = *(const int4*)(A2 + (size_t)gr * HID + (ks * 4 + q) * 8);
        af[ks][mi] = p.b;
      }
  };
  auto mf = [&](f32x4 (&acc)[4][2]) {
    #pragma unroll
    for (int ks = 0; ks < 4; ++ks) {
      int chunk = ks * 4 + q;
      bf16x8 b[2];
      #pragma unroll
      for (int ni = 0; ni < 2; ++ni)
        b[ni] = *(const bf16x8*)(sW + sidx(wave * 32 + ni * 16 + r16, chunk));
      #pragma unroll
      for (int mi = 0; mi < 4; ++mi)
        #pragma unroll
        for (int ni = 0; ni < 2; ++ni)
          acc[mi][ni] = __builtin_amdgcn_mfma_f32_16x16x32_bf16(af[ks][mi], b[ni], acc[mi][ni], 0, 0, 0);
    }
  };

  // pair 0: A1 feeds acc1 (Wa) then acc2 (Wc)
  stageW(Wa);
  __syncthreads();                 // covers A1-staging too
  loadA1();
  mf(acc1);
  __syncthreads();
  stageW(Wc);
  __syncthreads();
  mf(acc2);
  // pair 1: A2 (direct from global) feeds acc1 (Wb) then acc2 (Wd)
  loadA2g();                       // no barrier dependency
  __syncthreads();
  stageW(Wb);
  __syncthreads();
  mf(acc1);
  __syncthreads();
  stageW(Wd);
  __syncthreads();
  mf(acc2);

  #pragma unroll
  for (int ni = 0; ni < 2; ++ni) {
    int col = wave * 32 + ni * 16 + r16;
    float bv1 = bias1[col];
    float bv2 = bias2[col];
    #pragma unroll
    for (int mi = 0; mi < 4; ++mi)
      #pragma unroll
      for (int r = 0; r < 4; ++r) {
        int gr = m0 + mi * 16 + q * 4 + r;
        if (gr < M2o) {
          out1[(size_t)gr * HID + col] = f2b(fmaxf(acc1[mi][ni][r] + bv1, 0.f));
          out2[(size_t)gr * HID + col] = f2b(fmaxf(acc2[mi][ni][r] + bv2, 0.f));
        }
      }
  }
}

// ---------------- merged dual chain GEMM: us-chain + it-chain, one launch ----
__global__ __launch_bounds__(256) void k_chain2(
    const u16* __restrict__ A1a, const u16* __restrict__ W1a,
    const u16* __restrict__ A2a, const u16* __restrict__ W2a,
    const float* __restrict__ biasa, u16* __restrict__ outa, int Ma,
    const u16* __restrict__ Wlina, const float* __restrict__ blina,
    const u16* __restrict__ dW1a, const float* __restrict__ db1a,
    const u16* __restrict__ A1b, const u16* __restrict__ W1b,
    const u16* __restrict__ A2b, const u16* __restrict__ W2b,
    const float* __restrict__ biasb, u16* __restrict__ outb, int Mb,
    const u16* __restrict__ Wlinb, const float* __restrict__ blinb,
    const u16* __restrict__ dW1b, const float* __restrict__ db1b,
    int blkA) {
  __shared__ __align__(16) u16 sA[64 * HID];
  __shared__ __align__(16) u16 sW[128 * HID];
  const bool isA = (int)blockIdx.x < blkA;
  const u16* A1 = isA ? A1a : A1b;
  const u16* W1 = isA ? W1a : W1b;
  const u16* A2 = isA ? A2a : A2b;
  const u16* W2 = isA ? W2a : W2b;
  const float* bias = isA ? biasa : biasb;
  u16* out = isA ? outa : outb;
  const int M = isA ? Ma : Mb;
  const u16* Wlin = isA ? Wlina : Wlinb;
  const float* blin = isA ? blina : blinb;
  const u16* dW1 = isA ? dW1a : dW1b;
  const float* db1 = isA ? db1a : db1b;

  const int tid  = threadIdx.x;
  const int lane = tid & 63;
  const int wave = tid >> 6;
  const int q    = lane >> 4;
  const int r16  = lane & 15;
  const int m0   = (isA ? (int)blockIdx.x : (int)blockIdx.x - blkA) * 64;

  f32x4 acc[4][2];
  #pragma unroll
  for (int i = 0; i < 4; ++i)
    #pragma unroll
    for (int j = 0; j < 2; ++j) {
      acc[i][j][0] = 0.f; acc[i][j][1] = 0.f; acc[i][j][2] = 0.f; acc[i][j][3] = 0.f;
    }

  #pragma unroll
  for (int phase = 0; phase < 2; ++phase) {
    const u16* W = phase ? W2 : W1;
    const u16* A = phase ? A2 : A1;
    if (phase) __syncthreads();
    #pragma unroll
    for (int i = 0; i < 4; ++i) {
      int idx = i * 256 + tid;
      int rr = idx >> 4, c8 = idx & 15;
      int gr = m0 + rr;
      Pack8 p; p.v = make_int4(0, 0, 0, 0);
      if (gr < M) p.v = *(const int4*)(A + (size_t)gr * HID + c8 * 8);
      *(int4*)(sA + sidx(rr, c8)) = p.v;
    }
    #pragma unroll
    for (int i = 0; i < 8; ++i) {
      int idx = i * 256 + tid;
      int rr = idx >> 4, c8 = idx & 15;
      *(int4*)(sW + sidx(rr, c8)) = *(const int4*)(W + (size_t)rr * HID + c8 * 8);
    }
    __syncthreads();
    #pragma unroll
    for (int ks = 0; ks < 4; ++ks) {
      int chunk = ks * 4 + q;
      bf16x8 a[4], b[2];
      #pragma unroll
      for (int mi = 0; mi < 4; ++mi)
        a[mi] = *(const bf16x8*)(sA + sidx(mi * 16 + r16, chunk));
      #pragma unroll
      for (int ni = 0; ni < 2; ++ni)
        b[ni] = *(const bf16x8*)(sW + sidx(wave * 32 + ni * 16 + r16, chunk));
      #pragma unroll
      for (int mi = 0; mi < 4; ++mi)
        #pragma unroll
        for (int ni = 0; ni < 2; ++ni)
          acc[mi][ni] = __builtin_amdgcn_mfma_f32_16x16x32_bf16(a[mi], b[ni], acc[mi][ni], 0, 0, 0);
    }
  }

  // chain epilogue: T(relu) -> Z -> out, all in LDS
  __syncthreads();
  #pragma unroll
  for (int ni = 0; ni < 2; ++ni) {
    int col = wave * 32 + ni * 16 + r16;
    float bv = bias[col];
    #pragma unroll
    for (int mi = 0; mi < 4; ++mi)
      #pragma unroll
      for (int r = 0; r < 4; ++r) {
        int rl = mi * 16 + q * 4 + r;
        float v = fmaxf(acc[mi][ni][r] + bv, 0.f);
        sA[rl * HID + (((col >> 3) ^ (rl & 15)) << 3) + (col & 7)] = f2b(v);
      }
  }
  #pragma unroll
  for (int i = 0; i < 4; ++i) {
    int idx = i * 256 + tid;
    int rr = idx >> 4, c8 = idx & 15;
    *(int4*)(sW + sidx(rr, c8)) = *(const int4*)(Wlin + (size_t)rr * HID + c8 * 8);
  }
  #pragma unroll
  for (int i = 0; i < 2; ++i) {
    int idx = i * 256 + tid;
    int rr = idx >> 3, c8 = idx & 7;
    *(int4*)(sW + 8192 + sidx64(rr, c8)) = *(const int4*)(dW1 + (size_t)rr * HID + c8 * 8);
  }
  __syncthreads();
  f32x4 az[4];
  #pragma unroll
  for (int i = 0; i < 4; ++i) { az[i][0]=0.f; az[i][1]=0.f; az[i][2]=0.f; az[i][3]=0.f; }
  #pragma unroll
  for (int ks = 0; ks < 4; ++ks) {
    int chunk = ks * 4 + q;
    bf16x8 b = *(const bf16x8*)(sW + sidx(wave * 16 + r16, chunk));
    #pragma unroll
    for (int mi = 0; mi < 4; ++mi) {
      bf16x8 a = *(const bf16x8*)(sA + sidx(mi * 16 + r16, chunk));
      az[mi] = __builtin_amdgcn_mfma_f32_16x16x32_bf16(a, b, az[mi], 0, 0, 0);
    }
  }
  {
    int col = wave * 16 + r16;
    float bl = blin[col];
    #pragma unroll
    for (int mi = 0; mi < 4; ++mi)
      #pragma unroll
      for (int r = 0; r < 4; ++r) {
        int rl = mi * 16 + q * 4 + r;
        sW[12288 + rl * 64 + (((col >> 3) ^ (rl & 7)) << 3) + (col & 7)] = f2b(az[mi][r] + bl);
      }
  }
  __syncthreads();
  f32x4 au[4];
  #pragma unroll
  for (int i = 0; i < 4; ++i) { au[i][0]=0.f; au[i][1]=0.f; au[i][2]=0.f; au[i][3]=0.f; }
  #pragma unroll
  for (int ks = 0; ks < 2; ++ks) {
    int chunk = ks * 4 + q;
    bf16x8 b = *(const bf16x8*)(sW + 8192 + sidx64(wave * 16 + r16, chunk));
    #pragma unroll
    for (int mi = 0; mi < 4; ++mi) {
      bf16x8 a = *(const bf16x8*)(sW + 12288 + sidx64(mi * 16 + r16, chunk));
      au[mi] = __builtin_amdgcn_mfma_f32_16x16x32_bf16(a, b, au[mi], 0, 0, 0);
    }
  }
  {
    int col = wave * 16 + r16;
    float db = db1 ? db1[col] : 0.f;
    #pragma unroll
    for (int mi = 0; mi < 4; ++mi)
      #pragma unroll
      for (int r = 0; r < 4; ++r) {
        int gr = m0 + mi * 16 + q * 4 + r;
        if (gr < M) out[(size_t)gr * 64 + col] = f2b(au[mi][r] + db);
      }
  }
}

// ---------------- edge scorer: out[e] = w2 . relu(U[row]+V[col]) + b2 ---------
__global__ __launch_bounds__(256) void k_edge(const u16* __restrict__ U,
                                              const u16* __restrict__ V,
                                              const int* __restrict__ eli,
                                              const float* __restrict__ w2,
                                              const float* __restrict__ b2,
                                              float* __restrict__ out) {
  const int lane = threadIdx.x & 63;
  const int wave = threadIdx.x >> 6;
  const int se   = (lane >> 3);
  const int ch   = lane & 7;
  float w2c[8];
  #pragma unroll
  for (int j = 0; j < 8; ++j) w2c[j] = w2[ch * 8 + j];
  const float b2v = b2[0];
  const int e0 = blockIdx.x * 256;
  #pragma unroll
  for (int p = 0; p < 8; ++p) {
    int e = e0 + p * 32 + wave * 8 + se;
    if (e < ELB) {
      int r = eli[e];
      int c = eli[ELB + e];
      Pack8 pu, pv;
      pu.v = *(const int4*)(U + (size_t)r * 64 + ch * 8);
      pv.v = *(const int4*)(V + (size_t)c * 64 + ch * 8);
      float s = 0.f;
      #pragma unroll
      for (int j = 0; j < 8; ++j)
        s += fmaxf(b2f(pu.u[j]) + b2f(pv.u[j]), 0.f) * w2c[j];
      s += __shfl_xor(s, 1, 64);
      s += __shfl_xor(s, 2, 64);
      s += __shfl_xor(s, 4, 64);
      if (ch == 0) out[e] = s + b2v;
    }
  }
}

extern "C" void kernel_launch(void* const* d_in, const int* in_sizes, int n_in,
                              void* d_out, int out_size, void* d_ws, size_t ws_size,
                              hipStream_t stream) {
  const float* x_prod = (const float*)d_in[0];
  const float* x_cust = (const float*)d_in[1];
  const int* ei_pp    = (const int*)d_in[2];
  const int* ei_pc    = (const int*)d_in[3];
  const int* eli      = (const int*)d_in[4];

  const float *it_W1l, *it_W1r, *it_b1, *it_W2l, *it_W2r, *it_b2, *it_Wlin, *it_blin;
  const float *us_W1l, *us_W1r, *us_b1, *us_W2l, *us_W2r, *us_b2;
  const float *us_W3l, *us_W3r, *us_b3, *us_Wlin, *us_blin;
  if (in_sizes[6] == 128) {   // signature order (Wl, b, Wr)
    it_W1l  = (const float*)d_in[5];  it_b1   = (const float*)d_in[6];  it_W1r  = (const float*)d_in[7];
    it_W2l  = (const float*)d_in[8];  it_b2   = (const float*)d_in[9];  it_W2r  = (const float*)d_in[10];
    it_Wlin = (const float*)d_in[11]; it_blin = (const float*)d_in[12];
    us_W1l  = (const float*)d_in[13]; us_b1   = (const float*)d_in[14]; us_W1r  = (const float*)d_in[15];
    us_W2l  = (const float*)d_in[16]; us_b2   = (const float*)d_in[17]; us_W2r  = (const float*)d_in[18];
    us_W3l  = (const float*)d_in[19]; us_b3   = (const float*)d_in[20]; us_W3r  = (const float*)d_in[21];
    us_Wlin = (const float*)d_in[22]; us_blin = (const float*)d_in[23];
  } else {                    // setup_inputs dict order (Wl, Wr, b)
    it_W1l  = (const float*)d_in[5];  it_W1r  = (const float*)d_in[6];  it_b1   = (const float*)d_in[7];
    it_W2l  = (const float*)d_in[8];  it_W2r  = (const float*)d_in[9];  it_b2   = (const float*)d_in[10];
    it_Wlin = (const float*)d_in[11]; it_blin = (const float*)d_in[12];
    us_W1l  = (const float*)d_in[13]; us_W1r  = (const float*)d_in[14]; us_b1   = (const float*)d_in[15];
    us_W2l  = (const float*)d_in[16]; us_W2r  = (const float*)d_in[17]; us_b2   = (const float*)d_in[18];
    us_W3l  = (const float*)d_in[19]; us_W3r  = (const float*)d_in[20]; us_b3   = (const float*)d_in[21];
    us_Wlin = (const float*)d_in[22]; us_blin = (const float*)d_in[23];
  }
  const float* de_W1 = (const float*)d_in[24];
  const float* de_b1 = (const float*)d_in[25];
  const float* de_W2 = (const float*)d_in[26];
  const float* de_b2 = (const float*)d_in[27];

  char* ws = (char*)d_ws;
  int* bfill_pp = (int*)(ws + 0);              // 8*400*16*4 = 204800 B used (line-padded)
  int* bfill_pc = (int*)(ws + 409600);
  int* gctr     = (int*)(ws + 819200);         // 8 B (memset 0..819208)
  int* start_pp = (int*)(ws + 819264);
  int* cnt_pp   = (int*)(ws + 1219264);
  int* start_pc = (int*)(ws + 1619264);
  int* cnt_pc   = (int*)(ws + 1819264);
  int* esrc_pp  = (int*)(ws + 2019264);        // 3.2 MB \ U overlays after layer-2 aggs
  int* esrc_pc  = (int*)(ws + 5219264);        // 3.2 MB /
  u16* wbuf  = (u16*)(ws + 8419264);           // 376832 B
  u16* XPB   = (u16*)(ws + 8796096);           // 25.6 MB: bf16 x_prod -> PX (in place)
  u16* meanb = (u16*)(ws + 34396096);          // 25.6 MB: mean_pp1 -> mean_pp2
  u16* P1    = (u16*)(ws + 59996096);          // 25.6 MB: bss -> p1
  u16* meanc = (u16*)(ws + 85596096);          // 12.8 MB: mean_pc1 -> mean_pc2
  u16* CX    = (u16*)(ws + 98396096);          // 12.8 MB: cx -> V (peak ~111.2 MB)
  u32* bss_pp = (u32*)P1;                      // 391*8*512*4 = 6.1 MB
  u32* bss_pc = (u32*)(ws + 59996096 + 6553600);
  u16* PX = XPB;
  u16* U  = (u16*)esrc_pp;                     // 50000*64*2 = 6.4 MB exact
  u16* V  = CX;                                // 100000*64*2 = 12.8 MB exact

  u16* w_it1l = wbuf + 0 * 16384;  u16* w_it1r = wbuf + 1 * 16384;
  u16* w_it2l = wbuf + 2 * 16384;  u16* w_it2r = wbuf + 3 * 16384;
  u16* w_us1l = wbuf + 4 * 16384;  u16* w_us1r = wbuf + 5 * 16384;
  u16* w_us2l = wbuf + 6 * 16384;  u16* w_us2r = wbuf + 7 * 16384;
  u16* w_us3l = wbuf + 8 * 16384;  u16* w_us3r = wbuf + 9 * 16384;
  u16* w_itlin = wbuf + 10 * 16384;
  u16* w_uslin = wbuf + 10 * 16384 + 8192;
  u16* w_deW1  = wbuf + 10 * 16384 + 2 * 8192;

  (void)n_in; (void)out_size; (void)ws_size;

  hipMemsetAsync(d_ws, 0, 819208, stream);

  dim3 B(256);
  CastJobs jobs;
  jobs.src[0] = it_W1l;  jobs.src[1] = it_W1r;  jobs.src[2] = it_W2l;  jobs.src[3] = it_W2r;
  jobs.src[4] = us_W1l;  jobs.src[5] = us_W1r;  jobs.src[6] = us_W2l;  jobs.src[7] = us_W2r;
  jobs.src[8] = us_W3l;  jobs.src[9] = us_W3r;
  jobs.src[10] = it_Wlin; jobs.src[11] = us_Wlin; jobs.src[12] = de_W1;
  for (int i = 0; i < 10; ++i) jobs.n8[i] = 2048;
  for (int i = 10; i < 13; ++i) jobs.n8[i] = 1024;

  // merged preprocessing: bucket3 (392) + x_prod cast (6250) + weight cast (104)
  k_prep<<<dim3(NB3 + NCAST + NJOBS * 8), B, 0, stream>>>(
      ei_pp, ei_pc, bfill_pp, bfill_pc, bss_pp, bss_pc, x_prod, XPB, jobs, wbuf);
  // merged fine sort: pp (391) + pc (391)
  k_bsort2<<<dim3(2 * NBK), B, 0, stream>>>(bss_pp, bfill_pp, bss_pc, bfill_pc, gctr,
                                            esrc_pp, start_pp, cnt_pp,
                                            esrc_pc, start_pc, cnt_pc);

  dim3 Gp((NPROD + 63) / 64), Gc((NCUST + 63) / 64);
  const int App = (NPROD + 15) / 16, Apc = (NCUST + 15) / 16;

  // layer-1 means (pp + pc in one launch)
  k_agg2<<<dim3(App + Apc), B, 0, stream>>>(esrc_pp, start_pp, cnt_pp, XPB, meanb, NPROD,
                                            esrc_pc, start_pc, cnt_pc, XPB, meanc, NCUST, App);
  // merged layer-1 GEMMs: cx (782 blocks) + p1/px dual-output (1563 blocks)
  k_lay1<<<dim3(782 + 1563), B, 0, stream>>>(
      meanc, w_us2l, x_cust, w_us2r, us_b2, CX, NCUST,
      meanb, XPB, w_it1l, w_it1r, w_us1l, w_us1r,
      it_b1, us_b1, P1, PX, NPROD, 782);
  // layer-2 means (pp from P1, pc from PX, one launch)
  k_agg2<<<dim3(App + Apc), B, 0, stream>>>(esrc_pp, start_pp, cnt_pp, P1, meanb, NPROD,
                                            esrc_pc, start_pc, cnt_pc, PX, meanc, NCUST, App);
  // merged chains: us (cx2 -> z_cust -> U) + it (p2 -> z_prod -> V)
  k_chain2<<<dim3(782 + 1563), B, 0, stream>>>(
      meanc, w_us3l, CX, w_us3r, us_b3, U, NCUST, w_uslin, us_blin, w_deW1, de_b1,
      meanb, w_it2l, P1, w_it2r, it_b2, V, NPROD, w_itlin, it_blin, w_deW1 + 64, nullptr,
      782);
  // edge scoring
  k_edge<<<dim3((ELB + 255) / 256), B, 0, stream>>>(U, V, eli, de_W2, de_b2, (float*)d_out);
}